// Round 2
// baseline (290.356 us; speedup 1.0000x reference)
//
#include <hip/hip_runtime.h>

// ---------------------------------------------------------------------------
// SimpleBiquadEQ: 10-band peaking-EQ cascade (IIR) over [32,2,262144] fp32.
// Exact chunk-parallel state-passing scan. Round 2:
//  - passes: L=64, 4 independent chunk-chains per thread (ILP), LDS-staged
//    coalesced full-line stores in the output pass.
//  - scan: spill-free 3-phase (group Horner / KS over group totals / rewalk).
//  - fallback to round-1 pipeline if ws_size too small.
// ---------------------------------------------------------------------------

#define B_   32
#define C_   2
#define S_   262144
#define NB   10
#define SEQ  64

// ---------------- fast path config ----------------
#define F_LCH   64          // samples per chunk
#define F_PCH   4096        // chunks per sequence
#define F_NCH   4           // chains (chunks) per thread
#define F_G     8           // chunks per scan group
#define F_GRP   512         // groups per sequence (F_PCH/F_G)
#define F_NPOW  11          // A^2^6, A^2^8, A^2^9, A^2^10..A^2^17

// fast ws layout (floats)
#define F_OFF_POW 1600
#define F_OFF_T   142400            // 1600 + 32*11*400
#define F_OFF_G   5385280           // + 64*4096*20
#define F_OFF_SB  6040640           // + 64*512*20
#define F_TOT     6696000           // + 64*512*20  -> 26.78 MB

// ---------------- fallback (round-1) config ----------------
#define FB_LCH  256
#define FB_PCH  1024
#define FB_SUP  256
#define FB_NPOW 9
#define FB_OFF_POW 1600
#define FB_OFF_T   116800
#define FB_TOT     1427520          // 5.71 MB (known to fit)

// ===========================================================================
// coefficients (shared by both paths)
// ===========================================================================
__global__ void coef_kernel(const float* __restrict__ freqs,
                            const float* __restrict__ gains,
                            const float* __restrict__ qs,
                            float* __restrict__ coef) {
  int idx = blockIdx.x * blockDim.x + threadIdx.x;
  if (idx >= B_ * NB) return;
  float f = freqs[idx], g = gains[idx], Q = qs[idx];
  float w0 = 6.28318530717958648f * f / 44100.0f;
  float sw = sinf(w0), cw = cosf(w0);
  float alpha = sw / (2.0f * Q);
  float A = expf(g * 0.05756462732485114f);   // 10^(g/40)
  float aA = alpha * A, adA = alpha / A;
  float inv = 1.0f / (1.0f + adA);
  float* o = coef + idx * 5;
  o[0] = (1.0f + aA) * inv;     // b0
  o[1] = -2.0f * cw * inv;      // b1
  o[2] = (1.0f - aA) * inv;     // b2
  o[3] = 2.0f * cw * inv;       // -a1 (pre-negated)
  o[4] = -(1.0f - adA) * inv;   // -a2 (pre-negated)
}

// ===========================================================================
// shared matrix-build helper (device): build A into buf (row-major, 20x20)
// ===========================================================================
__device__ __forceinline__ void build_A_rows(const float* cf, float* bufA, int tid) {
  if (tid < 20) {
    int c = tid;
    float rp = 0.0f;
    for (int k = 0; k < NB; k++) {
      float b0 = cf[k*5+0], b1 = cf[k*5+1], b2 = cf[k*5+2];
      float na1 = cf[k*5+3], na2 = cf[k*5+4];
      float val = (k > 0) ? b0 * rp : 0.0f;
      if (k > 0) {
        if (c == 2*k-2) val += b1;
        if (c == 2*k-1) val += b2;
      }
      if (c == 2*k)   val += na1;
      if (c == 2*k+1) val += na2;
      bufA[2*k*20 + c] = val;
      rp = val;
      if (c == 2*k) bufA[(2*k+1)*20 + c] = 1.0f;
    }
  }
}

// ===========================================================================
// FAST PATH
// ===========================================================================

// powers: slot0=A^64, slot1=A^256, slot2=A^512, slot(3..10)=A^2^(10..17)
__global__ __launch_bounds__(256) void power_fast(const float* __restrict__ coef,
                                                  float* __restrict__ powers) {
  __shared__ float bufA[400], bufB[400];
  int b = blockIdx.x, tid = threadIdx.x;
  const float* cf = coef + b * NB * 5;
  for (int e = tid; e < 400; e += 256) bufA[e] = 0.0f;
  __syncthreads();
  build_A_rows(cf, bufA, tid);
  __syncthreads();
  float* cur = bufA;
  float* nxt = bufB;
  float* pw = powers + (size_t)b * F_NPOW * 400;
  for (int j = 1; j <= 17; j++) {
    for (int e = tid; e < 400; e += 256) {
      int r = e / 20, c = e % 20;
      float acc = 0.0f;
      #pragma unroll
      for (int k = 0; k < 20; k++) acc = fmaf(cur[r*20+k], cur[k*20+c], acc);
      nxt[e] = acc;
    }
    __syncthreads();
    { float* t_ = cur; cur = nxt; nxt = t_; }
    int slot = -1;
    if (j == 6) slot = 0;
    else if (j == 8) slot = 1;
    else if (j == 9) slot = 2;
    else if (j >= 10) slot = j - 7;
    if (slot >= 0) for (int e = tid; e < 400; e += 256) pw[slot*400 + e] = cur[e];
  }
}

// ---- pass 1: zero-state chunk run -> t (4 chains/thread, L=64) ----
__global__ __launch_bounds__(256, 1) void pass_false_fast(
    const float* __restrict__ x, const float* __restrict__ coef,
    float* __restrict__ t) {
  const int seq = blockIdx.y;
  const int b = seq >> 1;
  const int tid = threadIdx.x;
  const int wg0 = blockIdx.x * (256 * F_NCH);
  const float* cf = coef + b * NB * 5;
  float b0[NB], b1[NB], b2[NB], na1[NB], na2[NB];
  #pragma unroll
  for (int k = 0; k < NB; k++) {
    b0[k] = cf[k*5+0]; b1[k] = cf[k*5+1]; b2[k] = cf[k*5+2];
    na1[k] = cf[k*5+3]; na2[k] = cf[k*5+4];
  }
  int cidx[F_NCH];
  const float4* xv[F_NCH];
  float p[F_NCH][NB], q[F_NCH][NB], x1[F_NCH], x2[F_NCH];
  #pragma unroll
  for (int k = 0; k < F_NCH; k++) {
    cidx[k] = wg0 + k * 256 + tid;
    const float* xs = x + (size_t)seq * S_ + (size_t)cidx[k] * F_LCH;
    xv[k] = (const float4*)xs;
    x1[k] = 0.0f; x2[k] = 0.0f;
    if (cidx[k] > 0) { x1[k] = xs[-1]; x2[k] = xs[-2]; }
    #pragma unroll
    for (int kk = 0; kk < NB; kk++) { p[k][kk] = 0.0f; q[k][kk] = 0.0f; }
  }
  #pragma unroll 1
  for (int n4 = 0; n4 < F_LCH / 4; n4++) {
    #pragma unroll
    for (int k = 0; k < F_NCH; k++) {
      float4 xq = xv[k][n4];
      float xin[4] = {xq.x, xq.y, xq.z, xq.w};
      #pragma unroll
      for (int j = 0; j < 4; j++) {
        float u = xin[j], u1 = x1[k], u2 = x2[k];
        x2[k] = x1[k]; x1[k] = xin[j];
        #pragma unroll
        for (int kk = 0; kk < NB; kk++) {
          float v = fmaf(b0[kk], u,
                    fmaf(b1[kk], u1,
                    fmaf(b2[kk], u2,
                    fmaf(na1[kk], p[k][kk], na2[kk] * q[k][kk]))));
          u1 = p[k][kk]; u2 = q[k][kk];
          q[k][kk] = p[k][kk]; p[k][kk] = v;
          u = v;
        }
      }
    }
  }
  #pragma unroll
  for (int k = 0; k < F_NCH; k++) {
    float4* td = (float4*)(t + ((size_t)seq * F_PCH + cidx[k]) * 20);
    #pragma unroll
    for (int i = 0; i < 5; i++)
      td[i] = make_float4(p[k][2*i], q[k][2*i], p[k][2*i+1], q[k][2*i+1]);
  }
}

// ---- scan phase 1/3: per-group Horner walk with A^64 from LDS ----
template <bool WRITE_BACK>
__global__ __launch_bounds__(256) void scan_horner(
    float* __restrict__ t, const float* __restrict__ powers,
    float* __restrict__ gbuf, const float* __restrict__ sbuf) {
  __shared__ float Msh[400];        // A^64 transposed: Msh[c*20+r]=M[r][c]
  const int seq = blockIdx.y, b = seq >> 1;
  const int g = blockIdx.x * 256 + threadIdx.x;   // 0..511
  const float* pw0 = powers + (size_t)b * F_NPOW * 400;
  for (int e = threadIdx.x; e < 400; e += 256) {
    int r = e / 20, c = e % 20;
    Msh[c*20 + r] = pw0[e];
  }
  __syncthreads();
  float s[20];
  if (WRITE_BACK) {
    const float4* sv = (const float4*)(sbuf + ((size_t)seq * F_GRP + g) * 20);
    #pragma unroll
    for (int i = 0; i < 5; i++) {
      float4 a = sv[i];
      s[4*i] = a.x; s[4*i+1] = a.y; s[4*i+2] = a.z; s[4*i+3] = a.w;
    }
  } else {
    #pragma unroll
    for (int r = 0; r < 20; r++) s[r] = 0.0f;
  }
  float* tp = t + ((size_t)seq * F_PCH + (size_t)g * F_G) * 20;
  #pragma unroll 1
  for (int j = 0; j < F_G; j++) {
    float ns[20];
    const float4* tv = (const float4*)(tp + j * 20);
    #pragma unroll
    for (int i = 0; i < 5; i++) {
      float4 a = tv[i];
      ns[4*i] = a.x; ns[4*i+1] = a.y; ns[4*i+2] = a.z; ns[4*i+3] = a.w;
    }
    #pragma unroll
    for (int c = 0; c < 20; c++) {
      float vc = s[c];
      const float4* col = (const float4*)&Msh[c*20];
      float4 c0 = col[0], c1 = col[1], c2 = col[2], c3 = col[3], c4 = col[4];
      ns[0]  = fmaf(c0.x, vc, ns[0]);  ns[1]  = fmaf(c0.y, vc, ns[1]);
      ns[2]  = fmaf(c0.z, vc, ns[2]);  ns[3]  = fmaf(c0.w, vc, ns[3]);
      ns[4]  = fmaf(c1.x, vc, ns[4]);  ns[5]  = fmaf(c1.y, vc, ns[5]);
      ns[6]  = fmaf(c1.z, vc, ns[6]);  ns[7]  = fmaf(c1.w, vc, ns[7]);
      ns[8]  = fmaf(c2.x, vc, ns[8]);  ns[9]  = fmaf(c2.y, vc, ns[9]);
      ns[10] = fmaf(c2.z, vc, ns[10]); ns[11] = fmaf(c2.w, vc, ns[11]);
      ns[12] = fmaf(c3.x, vc, ns[12]); ns[13] = fmaf(c3.y, vc, ns[13]);
      ns[14] = fmaf(c3.z, vc, ns[14]); ns[15] = fmaf(c3.w, vc, ns[15]);
      ns[16] = fmaf(c4.x, vc, ns[16]); ns[17] = fmaf(c4.y, vc, ns[17]);
      ns[18] = fmaf(c4.z, vc, ns[18]); ns[19] = fmaf(c4.w, vc, ns[19]);
    }
    #pragma unroll
    for (int r = 0; r < 20; r++) s[r] = ns[r];
    if (WRITE_BACK) {
      float4* tw = (float4*)(tp + j * 20);
      #pragma unroll
      for (int i = 0; i < 5; i++)
        tw[i] = make_float4(s[4*i], s[4*i+1], s[4*i+2], s[4*i+3]);
    }
  }
  if (!WRITE_BACK) {
    float4* gw = (float4*)(gbuf + ((size_t)seq * F_GRP + g) * 20);
    #pragma unroll
    for (int i = 0; i < 5; i++)
      gw[i] = make_float4(s[4*i], s[4*i+1], s[4*i+2], s[4*i+3]);
  }
}

// ---- scan phase 2: Kogge-Stone over 512 group totals, one wg per seq ----
__global__ __launch_bounds__(512) void scan_ks(
    const float* __restrict__ gbuf, const float* __restrict__ powers,
    float* __restrict__ sbuf) {
  __shared__ float h[F_GRP * 20];   // 40 KB
  __shared__ float Ksh[400];        // transposed step matrix
  const int seq = blockIdx.x, b = seq >> 1, i = threadIdx.x;
  const float* pw = powers + (size_t)b * F_NPOW * 400;
  float own[20];
  {
    const float4* gv = (const float4*)(gbuf + ((size_t)seq * F_GRP + i) * 20);
    #pragma unroll
    for (int k = 0; k < 5; k++) {
      float4 a = gv[k];
      own[4*k] = a.x; own[4*k+1] = a.y; own[4*k+2] = a.z; own[4*k+3] = a.w;
    }
  }
  #pragma unroll
  for (int r = 0; r < 20; r++) h[i*20 + r] = own[r];
  for (int s = 0; s < 9; s++) {     // distances 1..256 groups (512 samples each)
    const int d = 1 << s;
    const float* pwS = pw + (size_t)(2 + s) * 400;   // A^(512*2^s)
    __syncthreads();
    for (int e = i; e < 400; e += 512) {
      int r = e / 20, c = e % 20;
      Ksh[c*20 + r] = pwS[e];
    }
    float nb[20];
    if (i >= d) {
      const float4* hv = (const float4*)&h[(i - d) * 20];
      #pragma unroll
      for (int k = 0; k < 5; k++) {
        float4 a = hv[k];
        nb[4*k] = a.x; nb[4*k+1] = a.y; nb[4*k+2] = a.z; nb[4*k+3] = a.w;
      }
    }
    __syncthreads();
    if (i >= d) {
      #pragma unroll
      for (int c = 0; c < 20; c++) {
        float vc = nb[c];
        const float4* col = (const float4*)&Ksh[c*20];
        float4 c0 = col[0], c1 = col[1], c2 = col[2], c3 = col[3], c4 = col[4];
        own[0]  = fmaf(c0.x, vc, own[0]);  own[1]  = fmaf(c0.y, vc, own[1]);
        own[2]  = fmaf(c0.z, vc, own[2]);  own[3]  = fmaf(c0.w, vc, own[3]);
        own[4]  = fmaf(c1.x, vc, own[4]);  own[5]  = fmaf(c1.y, vc, own[5]);
        own[6]  = fmaf(c1.z, vc, own[6]);  own[7]  = fmaf(c1.w, vc, own[7]);
        own[8]  = fmaf(c2.x, vc, own[8]);  own[9]  = fmaf(c2.y, vc, own[9]);
        own[10] = fmaf(c2.z, vc, own[10]); own[11] = fmaf(c2.w, vc, own[11]);
        own[12] = fmaf(c3.x, vc, own[12]); own[13] = fmaf(c3.w==c3.w?c3.y:c3.y, vc, own[13]);
        own[14] = fmaf(c3.z, vc, own[14]); own[15] = fmaf(c3.w, vc, own[15]);
        own[16] = fmaf(c4.x, vc, own[16]); own[17] = fmaf(c4.y, vc, own[17]);
        own[18] = fmaf(c4.z, vc, own[18]); own[19] = fmaf(c4.w, vc, own[19]);
      }
      #pragma unroll
      for (int r = 0; r < 20; r++) h[i*20 + r] = own[r];
    }
  }
  __syncthreads();
  float4* sw = (float4*)(sbuf + ((size_t)seq * F_GRP + i) * 20);
  if (i > 0) {
    const float4* hv = (const float4*)&h[(i - 1) * 20];
    #pragma unroll
    for (int k = 0; k < 5; k++) sw[k] = hv[k];
  } else {
    #pragma unroll
    for (int k = 0; k < 5; k++) sw[k] = make_float4(0.f, 0.f, 0.f, 0.f);
  }
}

// ---- pass 3: exact run from scanned state, LDS-staged coalesced stores ----
__global__ __launch_bounds__(256, 1) void pass_true_fast(
    const float* __restrict__ x, const float* __restrict__ coef,
    const float* __restrict__ t, float* __restrict__ out) {
  __shared__ float stash[2 * 256 * 16];   // 32 KB: chain-pair staging
  const int seq = blockIdx.y;
  const int b = seq >> 1;
  const int tid = threadIdx.x;
  const int wg0 = blockIdx.x * (256 * F_NCH);
  const float* cf = coef + b * NB * 5;
  float b0[NB], b1[NB], b2[NB], na1[NB], na2[NB];
  #pragma unroll
  for (int k = 0; k < NB; k++) {
    b0[k] = cf[k*5+0]; b1[k] = cf[k*5+1]; b2[k] = cf[k*5+2];
    na1[k] = cf[k*5+3]; na2[k] = cf[k*5+4];
  }
  int cidx[F_NCH];
  const float4* xv[F_NCH];
  float p[F_NCH][NB], q[F_NCH][NB], x1[F_NCH], x2[F_NCH];
  #pragma unroll
  for (int k = 0; k < F_NCH; k++) {
    cidx[k] = wg0 + k * 256 + tid;
    const float* xs = x + (size_t)seq * S_ + (size_t)cidx[k] * F_LCH;
    xv[k] = (const float4*)xs;
    x1[k] = 0.0f; x2[k] = 0.0f;
    if (cidx[k] > 0) { x1[k] = xs[-1]; x2[k] = xs[-2]; }
    if (cidx[k] > 0) {
      const float4* sv = (const float4*)(t + ((size_t)seq * F_PCH + cidx[k] - 1) * 20);
      #pragma unroll
      for (int i = 0; i < 5; i++) {
        float4 a = sv[i];
        p[k][2*i] = a.x; q[k][2*i] = a.y; p[k][2*i+1] = a.z; q[k][2*i+1] = a.w;
      }
    } else {
      #pragma unroll
      for (int kk = 0; kk < NB; kk++) { p[k][kk] = 0.0f; q[k][kk] = 0.0f; }
    }
  }
  float4* stashv = (float4*)stash;
  const size_t seqbase = (size_t)seq * S_;
  #pragma unroll 1
  for (int tile = 0; tile < 4; tile++) {
    float4 oreg[2][4];
    #pragma unroll 1
    for (int n4 = 0; n4 < 4; n4++) {
      #pragma unroll
      for (int k = 0; k < F_NCH; k++) {
        float4 xq = xv[k][tile*4 + n4];
        float xin[4] = {xq.x, xq.y, xq.z, xq.w};
        float o[4];
        #pragma unroll
        for (int j = 0; j < 4; j++) {
          float u = xin[j], u1 = x1[k], u2 = x2[k];
          x2[k] = x1[k]; x1[k] = xin[j];
          #pragma unroll
          for (int kk = 0; kk < NB; kk++) {
            float v = fmaf(b0[kk], u,
                      fmaf(b1[kk], u1,
                      fmaf(b2[kk], u2,
                      fmaf(na1[kk], p[k][kk], na2[kk] * q[k][kk]))));
            u1 = p[k][kk]; u2 = q[k][kk];
            q[k][kk] = p[k][kk]; p[k][kk] = v;
            u = v;
          }
          o[j] = u;
        }
        float4 of = make_float4(o[0], o[1], o[2], o[3]);
        if (k < 2) stashv[(k*256 + tid)*4 + n4] = of;
        else       oreg[k-2][n4] = of;
      }
    }
    // pair 0: chains 0,1 -> chunks [wg0, wg0+512)
    __syncthreads();
    #pragma unroll
    for (int i = 0; i < 8; i++) {
      int f = tid + i * 256;               // float4 segment id, 0..2047
      int chunkIdx = f >> 2, w = f & 3;
      float4 v = stashv[f];
      float4* op = (float4*)(out + seqbase + (size_t)(wg0 + chunkIdx) * F_LCH + tile*16);
      op[w] = v;
    }
    __syncthreads();
    #pragma unroll
    for (int k2 = 0; k2 < 2; k2++)
      #pragma unroll
      for (int n4 = 0; n4 < 4; n4++)
        stashv[(k2*256 + tid)*4 + n4] = oreg[k2][n4];
    __syncthreads();
    // pair 1: chains 2,3 -> chunks [wg0+512, wg0+1024)
    #pragma unroll
    for (int i = 0; i < 8; i++) {
      int f = tid + i * 256;
      int chunkIdx = f >> 2, w = f & 3;
      float4 v = stashv[f];
      float4* op = (float4*)(out + seqbase + (size_t)(wg0 + 512 + chunkIdx) * F_LCH + tile*16);
      op[w] = v;
    }
    __syncthreads();
  }
}

// ===========================================================================
// FALLBACK PATH (round-1, known-good, 5.71 MB ws)
// ===========================================================================
__global__ __launch_bounds__(256) void power_fb(const float* __restrict__ coef,
                                                float* __restrict__ powers) {
  __shared__ float bufA[400], bufB[400];
  int b = blockIdx.x, tid = threadIdx.x;
  const float* cf = coef + b * NB * 5;
  for (int e = tid; e < 400; e += 256) bufA[e] = 0.0f;
  __syncthreads();
  build_A_rows(cf, bufA, tid);
  __syncthreads();
  float* cur = bufA;
  float* nxt = bufB;
  float* pw = powers + (size_t)b * FB_NPOW * 400;
  for (int j = 1; j <= 17; j++) {
    for (int e = tid; e < 400; e += 256) {
      int r = e / 20, c = e % 20;
      float acc = 0.0f;
      #pragma unroll
      for (int k = 0; k < 20; k++) acc = fmaf(cur[r*20+k], cur[k*20+c], acc);
      nxt[e] = acc;
    }
    __syncthreads();
    { float* t_ = cur; cur = nxt; nxt = t_; }
    if (j == 8)  for (int e = tid; e < 400; e += 256) pw[e] = cur[e];
    if (j >= 10) for (int e = tid; e < 400; e += 256) pw[(j-9)*400 + e] = cur[e];
  }
}

template <bool WRITE_OUT>
__global__ __launch_bounds__(256) void pass_fb(const float* __restrict__ x,
                                               const float* __restrict__ coef,
                                               const float* __restrict__ sc,
                                               float* __restrict__ tout,
                                               float* __restrict__ out) {
  const int seq = blockIdx.y;
  const int b = seq >> 1;
  const int chunk = blockIdx.x * blockDim.x + threadIdx.x;
  const float* cf = coef + b * NB * 5;
  float b0[NB], b1[NB], b2[NB], na1[NB], na2[NB];
  #pragma unroll
  for (int k = 0; k < NB; k++) {
    b0[k] = cf[k*5+0]; b1[k] = cf[k*5+1]; b2[k] = cf[k*5+2];
    na1[k] = cf[k*5+3]; na2[k] = cf[k*5+4];
  }
  const float* xs = x + (size_t)seq * S_ + (size_t)chunk * FB_LCH;
  float p[NB], q[NB];
  float x1 = 0.0f, x2 = 0.0f;
  if (chunk > 0) { x1 = xs[-1]; x2 = xs[-2]; }
  if (WRITE_OUT && chunk > 0) {
    const float* s0 = sc + ((size_t)seq * FB_PCH + (chunk - 1)) * 20;
    #pragma unroll
    for (int k = 0; k < NB; k++) { p[k] = s0[2*k]; q[k] = s0[2*k+1]; }
  } else {
    #pragma unroll
    for (int k = 0; k < NB; k++) { p[k] = 0.0f; q[k] = 0.0f; }
  }
  const float4* xvv = (const float4*)xs;
  float4* ov = nullptr;
  if (WRITE_OUT) ov = (float4*)(out + (size_t)seq * S_ + (size_t)chunk * FB_LCH);
  #pragma unroll 1
  for (int n4 = 0; n4 < FB_LCH / 4; n4++) {
    float4 xq = xvv[n4];
    float xin[4] = {xq.x, xq.y, xq.z, xq.w};
    float o[4];
    #pragma unroll
    for (int j = 0; j < 4; j++) {
      float u = xin[j], u1 = x1, u2 = x2;
      x2 = x1; x1 = xin[j];
      #pragma unroll
      for (int k = 0; k < NB; k++) {
        float v = fmaf(b0[k], u,
                  fmaf(b1[k], u1,
                  fmaf(b2[k], u2,
                  fmaf(na1[k], p[k], na2[k] * q[k]))));
        u1 = p[k]; u2 = q[k];
        q[k] = p[k]; p[k] = v;
        u = v;
      }
      o[j] = u;
    }
    if (WRITE_OUT) ov[n4] = make_float4(o[0], o[1], o[2], o[3]);
  }
  if (!WRITE_OUT) {
    float* td = tout + ((size_t)seq * FB_PCH + chunk) * 20;
    #pragma unroll
    for (int k = 0; k < NB; k++) { td[2*k] = p[k]; td[2*k+1] = q[k]; }
  }
}

__device__ __forceinline__ void mv20_fb(float* __restrict__ o, const float* M,
                                        const float* v) {
  #pragma unroll
  for (int r = 0; r < 20; r++) {
    float acc = 0.0f;
    #pragma unroll
    for (int c = 0; c < 20; c++) acc = fmaf(M[r*20+c], v[c], acc);
    o[r] = acc;
  }
}

__global__ __launch_bounds__(256) void scan_fb(float* __restrict__ t,
                                               const float* __restrict__ powers) {
  __shared__ float h[FB_SUP * 21];
  __shared__ float Msh[400];
  __shared__ float Ksh[400];
  const int seq = blockIdx.x, b = seq >> 1, i = threadIdx.x;
  const float* pw = powers + (size_t)b * FB_NPOW * 400;
  for (int e = i; e < 400; e += 256) Msh[e] = pw[e];
  __syncthreads();
  float* tb = t + (size_t)seq * FB_PCH * 20;
  float u0[20], u1[20], u2[20], own[20], tmp[20];
  #pragma unroll
  for (int r = 0; r < 20; r++) u0[r] = tb[(4*i + 0)*20 + r];
  mv20_fb(u1, Msh, u0);
  #pragma unroll
  for (int r = 0; r < 20; r++) u1[r] += tb[(4*i + 1)*20 + r];
  mv20_fb(u2, Msh, u1);
  #pragma unroll
  for (int r = 0; r < 20; r++) u2[r] += tb[(4*i + 2)*20 + r];
  mv20_fb(own, Msh, u2);
  #pragma unroll
  for (int r = 0; r < 20; r++) own[r] += tb[(4*i + 3)*20 + r];
  #pragma unroll
  for (int r = 0; r < 20; r++) h[i*21 + r] = own[r];
  for (int s = 0; s < 8; s++) {
    const int d = 1 << s;
    __syncthreads();
    for (int e = i; e < 400; e += 256) Ksh[e] = pw[(1 + s)*400 + e];
    __syncthreads();
    float nb[20];
    if (i >= d) {
      #pragma unroll
      for (int r = 0; r < 20; r++) nb[r] = h[(i - d)*21 + r];
    }
    __syncthreads();
    if (i >= d) {
      mv20_fb(tmp, Ksh, nb);
      #pragma unroll
      for (int r = 0; r < 20; r++) { own[r] += tmp[r]; h[i*21 + r] = own[r]; }
    }
  }
  __syncthreads();
  float Pi[20];
  if (i > 0) {
    #pragma unroll
    for (int r = 0; r < 20; r++) Pi[r] = h[(i - 1)*21 + r];
  } else {
    #pragma unroll
    for (int r = 0; r < 20; r++) Pi[r] = 0.0f;
  }
  float w[20];
  mv20_fb(w, Msh, Pi);
  #pragma unroll
  for (int r = 0; r < 20; r++) tb[(4*i + 0)*20 + r] = w[r] + u0[r];
  mv20_fb(tmp, Msh, w);
  #pragma unroll
  for (int r = 0; r < 20; r++) tb[(4*i + 1)*20 + r] = tmp[r] + u1[r];
  mv20_fb(w, Msh, tmp);
  #pragma unroll
  for (int r = 0; r < 20; r++) tb[(4*i + 2)*20 + r] = w[r] + u2[r];
  #pragma unroll
  for (int r = 0; r < 20; r++) tb[(4*i + 3)*20 + r] = own[r];
}

// ===========================================================================
extern "C" void kernel_launch(void* const* d_in, const int* in_sizes, int n_in,
                              void* d_out, int out_size, void* d_ws, size_t ws_size,
                              hipStream_t stream) {
  const float* audio = (const float*)d_in[0];
  const float* freqs = (const float*)d_in[1];
  const float* gains = (const float*)d_in[2];
  const float* qs    = (const float*)d_in[3];
  float* out = (float*)d_out;
  float* ws  = (float*)d_ws;
  float* coef = ws;

  hipLaunchKernelGGL(coef_kernel, dim3(5), dim3(64), 0, stream,
                     freqs, gains, qs, coef);

  if (ws_size >= (size_t)F_TOT * sizeof(float)) {
    float* powers = ws + F_OFF_POW;
    float* t      = ws + F_OFF_T;
    float* gbuf   = ws + F_OFF_G;
    float* sbuf   = ws + F_OFF_SB;
    hipLaunchKernelGGL(power_fast, dim3(B_), dim3(256), 0, stream, coef, powers);
    hipLaunchKernelGGL(pass_false_fast, dim3(F_PCH / (256 * F_NCH), SEQ), dim3(256),
                       0, stream, audio, coef, t);
    hipLaunchKernelGGL((scan_horner<false>), dim3(F_GRP / 256, SEQ), dim3(256),
                       0, stream, t, powers, gbuf, (const float*)nullptr);
    hipLaunchKernelGGL(scan_ks, dim3(SEQ), dim3(512), 0, stream,
                       gbuf, powers, sbuf);
    hipLaunchKernelGGL((scan_horner<true>), dim3(F_GRP / 256, SEQ), dim3(256),
                       0, stream, t, powers, (float*)nullptr, sbuf);
    hipLaunchKernelGGL(pass_true_fast, dim3(F_PCH / (256 * F_NCH), SEQ), dim3(256),
                       0, stream, audio, coef, t, out);
  } else {
    float* powers = ws + FB_OFF_POW;
    float* t      = ws + FB_OFF_T;
    hipLaunchKernelGGL(power_fb, dim3(B_), dim3(256), 0, stream, coef, powers);
    hipLaunchKernelGGL((pass_fb<false>), dim3(FB_PCH / 256, SEQ), dim3(256), 0, stream,
                       audio, coef, (const float*)nullptr, t, (float*)nullptr);
    hipLaunchKernelGGL(scan_fb, dim3(SEQ), dim3(256), 0, stream, t, powers);
    hipLaunchKernelGGL((pass_fb<true>), dim3(FB_PCH / 256, SEQ), dim3(256), 0, stream,
                       audio, coef, t, (float*)nullptr, out);
  }
}

// Round 3
// 236.118 us; speedup vs baseline: 1.2297x; 1.2297x over previous
//
#include <hip/hip_runtime.h>

// ---------------------------------------------------------------------------
// SimpleBiquadEQ: 10-band peaking-EQ cascade (IIR) over [32,2,262144] fp32.
// Exact chunk-parallel state-passing scan. Round 3:
//  - passes: wg=64 (1 wave) owns 64 contiguous chunks (L=64, 16 KB span).
//    Coalesced global<->LDS staging with XOR-swizzled float4 layout
//    (conflict-free b128 both directions), 1 chunk per lane from LDS.
//    pass_true writes y in-place over x in LDS, then linear coalesced store.
//  - setup: coef + matrix powers fused into one kernel.
//  - scan: 3-phase (Horner G=8 / KS over 512 totals / rewalk), as validated
//    in round 2, with 1-deep load prefetch in the Horner phases.
// ---------------------------------------------------------------------------

#define B_   32
#define C_   2
#define S_   262144
#define NB   10
#define SEQ  64

#define F_LCH   64          // samples per chunk
#define F_PCH   4096        // chunks per sequence
#define F_G     8           // chunks per scan group
#define F_GRP   512         // groups per sequence
#define F_NPOW  11          // slot0=A^64, slot1=A^256, slot2..10=A^(512*2^s)

// ws layout (floats)
#define F_OFF_POW 1600
#define F_OFF_T   142400            // 1600 + 32*11*400
#define F_OFF_G   5385280           // + 64*4096*20
#define F_OFF_SB  6040640           // + 64*512*20
#define F_TOT     6696000           // 26.78 MB (fits: round-2 ran this layout)

// ===========================================================================
// setup: coefficients + matrix powers (fused)
// ===========================================================================
__global__ __launch_bounds__(256) void setup_kernel(
    const float* __restrict__ freqs, const float* __restrict__ gains,
    const float* __restrict__ qs, float* __restrict__ coef,
    float* __restrict__ powers) {
  __shared__ float bufA[400], bufB[400];
  __shared__ float cfs[NB * 5];
  const int b = blockIdx.x, tid = threadIdx.x;
  for (int e = tid; e < 400; e += 256) bufA[e] = 0.0f;
  if (tid < NB) {
    int idx = b * NB + tid;
    float f = freqs[idx], g = gains[idx], Q = qs[idx];
    float w0 = 6.28318530717958648f * f / 44100.0f;
    float sw = sinf(w0), cw = cosf(w0);
    float alpha = sw / (2.0f * Q);
    float A = expf(g * 0.05756462732485114f);   // 10^(g/40)
    float aA = alpha * A, adA = alpha / A;
    float inv = 1.0f / (1.0f + adA);
    float c0 = (1.0f + aA) * inv;
    float c1 = -2.0f * cw * inv;
    float c2 = (1.0f - aA) * inv;
    float c3 = 2.0f * cw * inv;      // -a1
    float c4 = -(1.0f - adA) * inv;  // -a2
    cfs[tid*5+0] = c0; cfs[tid*5+1] = c1; cfs[tid*5+2] = c2;
    cfs[tid*5+3] = c3; cfs[tid*5+4] = c4;
    float* o = coef + idx * 5;
    o[0] = c0; o[1] = c1; o[2] = c2; o[3] = c3; o[4] = c4;
  }
  __syncthreads();
  // build A (rows p_k at 2k, q_k at 2k+1); thread tid<20 owns column tid
  if (tid < 20) {
    int c = tid;
    float rp = 0.0f;
    for (int k = 0; k < NB; k++) {
      float b0 = cfs[k*5+0], b1 = cfs[k*5+1], b2 = cfs[k*5+2];
      float na1 = cfs[k*5+3], na2 = cfs[k*5+4];
      float val = (k > 0) ? b0 * rp : 0.0f;
      if (k > 0) {
        if (c == 2*k-2) val += b1;
        if (c == 2*k-1) val += b2;
      }
      if (c == 2*k)   val += na1;
      if (c == 2*k+1) val += na2;
      bufA[2*k*20 + c] = val;
      rp = val;
      if (c == 2*k) bufA[(2*k+1)*20 + c] = 1.0f;
    }
  }
  __syncthreads();
  float* cur = bufA;
  float* nxt = bufB;
  float* pw = powers + (size_t)b * F_NPOW * 400;
  for (int j = 1; j <= 17; j++) {   // cur becomes A^(2^j)
    for (int e = tid; e < 400; e += 256) {
      int r = e / 20, c = e % 20;
      float acc = 0.0f;
      #pragma unroll
      for (int k = 0; k < 20; k++) acc = fmaf(cur[r*20+k], cur[k*20+c], acc);
      nxt[e] = acc;
    }
    __syncthreads();
    { float* t_ = cur; cur = nxt; nxt = t_; }
    int slot = -1;
    if (j == 6) slot = 0;            // A^64
    else if (j == 8) slot = 1;       // A^256 (unused, kept for layout)
    else if (j == 9) slot = 2;       // A^512
    else if (j >= 10) slot = j - 7;  // A^1024..A^131072
    if (slot >= 0) for (int e = tid; e < 400; e += 256) pw[slot*400 + e] = cur[e];
  }
}

// ===========================================================================
// passes: 1 wave per wg, 64 contiguous chunks, XOR-swizzled LDS transpose.
// swizzle: float4 (chunk c, quad q) lives at lds4[c*16 + (q ^ (c & 15))]
// ===========================================================================
template <bool WRITE_OUT>
__global__ __launch_bounds__(64) void pass_v3(
    const float* __restrict__ x, const float* __restrict__ coef,
    const float* __restrict__ tst, float* __restrict__ tout,
    float* __restrict__ out) {
  __shared__ float4 lds4[1024];     // 16 KB: 64 chunks x 16 float4
  const int seq = blockIdx.y;
  const int b = seq >> 1;
  const int lane = threadIdx.x;
  const int wgc0 = blockIdx.x * 64;          // first chunk of this wg
  const int chunk = wgc0 + lane;
  const float* cf = coef + b * NB * 5;       // uniform -> scalar loads
  float b0[NB], b1[NB], b2[NB], na1[NB], na2[NB];
  #pragma unroll
  for (int k = 0; k < NB; k++) {
    b0[k] = cf[k*5+0]; b1[k] = cf[k*5+1]; b2[k] = cf[k*5+2];
    na1[k] = cf[k*5+3]; na2[k] = cf[k*5+4];
  }
  // ---- stage: coalesced global -> swizzled LDS (1024 float4 per wg) ----
  const size_t span0 = (size_t)seq * S_ + (size_t)wgc0 * F_LCH;  // floats
  const float4* gx = (const float4*)(x + span0);
  #pragma unroll 4
  for (int it = 0; it < 16; it++) {
    int f = it * 64 + lane;
    float4 v = gx[f];
    int c = f >> 4, q = f & 15;
    lds4[c*16 + (q ^ (c & 15))] = v;
  }
  __syncthreads();
  // ---- init state ----
  float x1 = 0.0f, x2 = 0.0f;
  if (lane == 0) {
    if (chunk > 0) {
      const float* xs = x + span0;
      x1 = xs[-1]; x2 = xs[-2];
    }
  } else {
    float4 pv = lds4[(lane-1)*16 + (15 ^ ((lane-1) & 15))];
    x2 = pv.z; x1 = pv.w;
  }
  float p[NB], q_[NB];
  if (WRITE_OUT && chunk > 0) {
    const float4* sv = (const float4*)(tst + ((size_t)seq * F_PCH + chunk - 1) * 20);
    #pragma unroll
    for (int i = 0; i < 5; i++) {
      float4 a = sv[i];
      p[2*i] = a.x; q_[2*i] = a.y; p[2*i+1] = a.z; q_[2*i+1] = a.w;
    }
  } else {
    #pragma unroll
    for (int k = 0; k < NB; k++) { p[k] = 0.0f; q_[k] = 0.0f; }
  }
  // ---- compute: my chunk = lane, 16 float4 from LDS ----
  #pragma unroll 2
  for (int qq = 0; qq < 16; qq++) {
    const int slot = lane*16 + (qq ^ (lane & 15));
    float4 xv = lds4[slot];
    float xin[4] = {xv.x, xv.y, xv.z, xv.w};
    float o[4];
    #pragma unroll
    for (int j = 0; j < 4; j++) {
      float u = xin[j], u1 = x1, u2 = x2;
      x2 = x1; x1 = xin[j];
      #pragma unroll
      for (int k = 0; k < NB; k++) {
        float v = fmaf(b0[k], u,
                  fmaf(b1[k], u1,
                  fmaf(b2[k], u2,
                  fmaf(na1[k], p[k], na2[k] * q_[k]))));
        u1 = p[k]; u2 = q_[k];
        q_[k] = p[k]; p[k] = v;
        u = v;
      }
      o[j] = u;
    }
    if (WRITE_OUT) lds4[slot] = make_float4(o[0], o[1], o[2], o[3]);  // in-place
  }
  if (WRITE_OUT) {
    __syncthreads();
    float4* gy = (float4*)(out + span0);
    #pragma unroll 4
    for (int it = 0; it < 16; it++) {
      int f = it * 64 + lane;
      int c = f >> 4, q = f & 15;
      gy[f] = lds4[c*16 + (q ^ (c & 15))];
    }
  } else {
    float4* td = (float4*)(tout + ((size_t)seq * F_PCH + chunk) * 20);
    #pragma unroll
    for (int i = 0; i < 5; i++)
      td[i] = make_float4(p[2*i], q_[2*i], p[2*i+1], q_[2*i+1]);
  }
}

// ===========================================================================
// scan phase 1/3: per-group Horner walk with A^64 (transposed in LDS)
// ===========================================================================
template <bool WRITE_BACK>
__global__ __launch_bounds__(256) void scan_horner(
    float* __restrict__ t, const float* __restrict__ powers,
    float* __restrict__ gbuf, const float* __restrict__ sbuf) {
  __shared__ float Msh[400];        // Msh[c*20+r] = M[r][c]
  const int seq = blockIdx.y, b = seq >> 1;
  const int g = blockIdx.x * 256 + threadIdx.x;   // 0..511
  const float* pw0 = powers + (size_t)b * F_NPOW * 400;
  for (int e = threadIdx.x; e < 400; e += 256) {
    int r = e / 20, c = e % 20;
    Msh[c*20 + r] = pw0[e];
  }
  __syncthreads();
  float s[20];
  if (WRITE_BACK) {
    const float4* sv = (const float4*)(sbuf + ((size_t)seq * F_GRP + g) * 20);
    #pragma unroll
    for (int i = 0; i < 5; i++) {
      float4 a = sv[i];
      s[4*i] = a.x; s[4*i+1] = a.y; s[4*i+2] = a.z; s[4*i+3] = a.w;
    }
  } else {
    #pragma unroll
    for (int r = 0; r < 20; r++) s[r] = 0.0f;
  }
  float* tp = t + ((size_t)seq * F_PCH + (size_t)g * F_G) * 20;
  const float4* tv = (const float4*)tp;
  float4 nx[5];
  #pragma unroll
  for (int i = 0; i < 5; i++) nx[i] = tv[i];      // prefetch j=0
  #pragma unroll 1
  for (int j = 0; j < F_G; j++) {
    float ns[20];
    #pragma unroll
    for (int i = 0; i < 5; i++) {
      float4 a = nx[i];
      ns[4*i] = a.x; ns[4*i+1] = a.y; ns[4*i+2] = a.z; ns[4*i+3] = a.w;
    }
    if (j < F_G - 1) {
      #pragma unroll
      for (int i = 0; i < 5; i++) nx[i] = tv[(j+1)*5 + i];   // prefetch next
    }
    #pragma unroll
    for (int c = 0; c < 20; c++) {
      float vc = s[c];
      const float4* col = (const float4*)&Msh[c*20];
      float4 c0 = col[0], c1 = col[1], c2 = col[2], c3 = col[3], c4 = col[4];
      ns[0]  = fmaf(c0.x, vc, ns[0]);  ns[1]  = fmaf(c0.y, vc, ns[1]);
      ns[2]  = fmaf(c0.z, vc, ns[2]);  ns[3]  = fmaf(c0.w, vc, ns[3]);
      ns[4]  = fmaf(c1.x, vc, ns[4]);  ns[5]  = fmaf(c1.y, vc, ns[5]);
      ns[6]  = fmaf(c1.z, vc, ns[6]);  ns[7]  = fmaf(c1.w, vc, ns[7]);
      ns[8]  = fmaf(c2.x, vc, ns[8]);  ns[9]  = fmaf(c2.y, vc, ns[9]);
      ns[10] = fmaf(c2.z, vc, ns[10]); ns[11] = fmaf(c2.w, vc, ns[11]);
      ns[12] = fmaf(c3.x, vc, ns[12]); ns[13] = fmaf(c3.y, vc, ns[13]);
      ns[14] = fmaf(c3.z, vc, ns[14]); ns[15] = fmaf(c3.w, vc, ns[15]);
      ns[16] = fmaf(c4.x, vc, ns[16]); ns[17] = fmaf(c4.y, vc, ns[17]);
      ns[18] = fmaf(c4.z, vc, ns[18]); ns[19] = fmaf(c4.w, vc, ns[19]);
    }
    #pragma unroll
    for (int r = 0; r < 20; r++) s[r] = ns[r];
    if (WRITE_BACK) {
      float4* tw = (float4*)(tp + j * 20);
      #pragma unroll
      for (int i = 0; i < 5; i++)
        tw[i] = make_float4(s[4*i], s[4*i+1], s[4*i+2], s[4*i+3]);
    }
  }
  if (!WRITE_BACK) {
    float4* gw = (float4*)(gbuf + ((size_t)seq * F_GRP + g) * 20);
    #pragma unroll
    for (int i = 0; i < 5; i++)
      gw[i] = make_float4(s[4*i], s[4*i+1], s[4*i+2], s[4*i+3]);
  }
}

// ===========================================================================
// scan phase 2: Kogge-Stone over 512 group totals, one wg per sequence
// ===========================================================================
__global__ __launch_bounds__(512) void scan_ks(
    const float* __restrict__ gbuf, const float* __restrict__ powers,
    float* __restrict__ sbuf) {
  __shared__ float h[F_GRP * 20];   // 40 KB
  __shared__ float Ksh[400];        // transposed step matrix
  const int seq = blockIdx.x, b = seq >> 1, i = threadIdx.x;
  const float* pw = powers + (size_t)b * F_NPOW * 400;
  float own[20];
  {
    const float4* gv = (const float4*)(gbuf + ((size_t)seq * F_GRP + i) * 20);
    #pragma unroll
    for (int k = 0; k < 5; k++) {
      float4 a = gv[k];
      own[4*k] = a.x; own[4*k+1] = a.y; own[4*k+2] = a.z; own[4*k+3] = a.w;
    }
  }
  #pragma unroll
  for (int r = 0; r < 20; r++) h[i*20 + r] = own[r];
  for (int s = 0; s < 9; s++) {     // distances 1..256 groups
    const int d = 1 << s;
    const float* pwS = pw + (size_t)(2 + s) * 400;   // A^(512*2^s)
    __syncthreads();
    for (int e = i; e < 400; e += 512) {
      int r = e / 20, c = e % 20;
      Ksh[c*20 + r] = pwS[e];
    }
    float nb[20];
    if (i >= d) {
      const float4* hv = (const float4*)&h[(i - d) * 20];
      #pragma unroll
      for (int k = 0; k < 5; k++) {
        float4 a = hv[k];
        nb[4*k] = a.x; nb[4*k+1] = a.y; nb[4*k+2] = a.z; nb[4*k+3] = a.w;
      }
    }
    __syncthreads();
    if (i >= d) {
      #pragma unroll
      for (int c = 0; c < 20; c++) {
        float vc = nb[c];
        const float4* col = (const float4*)&Ksh[c*20];
        float4 c0 = col[0], c1 = col[1], c2 = col[2], c3 = col[3], c4 = col[4];
        own[0]  = fmaf(c0.x, vc, own[0]);  own[1]  = fmaf(c0.y, vc, own[1]);
        own[2]  = fmaf(c0.z, vc, own[2]);  own[3]  = fmaf(c0.w, vc, own[3]);
        own[4]  = fmaf(c1.x, vc, own[4]);  own[5]  = fmaf(c1.y, vc, own[5]);
        own[6]  = fmaf(c1.z, vc, own[6]);  own[7]  = fmaf(c1.w, vc, own[7]);
        own[8]  = fmaf(c2.x, vc, own[8]);  own[9]  = fmaf(c2.y, vc, own[9]);
        own[10] = fmaf(c2.z, vc, own[10]); own[11] = fmaf(c2.w, vc, own[11]);
        own[12] = fmaf(c3.x, vc, own[12]); own[13] = fmaf(c3.y, vc, own[13]);
        own[14] = fmaf(c3.z, vc, own[14]); own[15] = fmaf(c3.w, vc, own[15]);
        own[16] = fmaf(c4.x, vc, own[16]); own[17] = fmaf(c4.y, vc, own[17]);
        own[18] = fmaf(c4.z, vc, own[18]); own[19] = fmaf(c4.w, vc, own[19]);
      }
      #pragma unroll
      for (int r = 0; r < 20; r++) h[i*20 + r] = own[r];
    }
  }
  __syncthreads();
  float4* sw = (float4*)(sbuf + ((size_t)seq * F_GRP + i) * 20);
  if (i > 0) {
    const float4* hv = (const float4*)&h[(i - 1) * 20];
    #pragma unroll
    for (int k = 0; k < 5; k++) sw[k] = hv[k];
  } else {
    #pragma unroll
    for (int k = 0; k < 5; k++) sw[k] = make_float4(0.f, 0.f, 0.f, 0.f);
  }
}

// ===========================================================================
extern "C" void kernel_launch(void* const* d_in, const int* in_sizes, int n_in,
                              void* d_out, int out_size, void* d_ws, size_t ws_size,
                              hipStream_t stream) {
  const float* audio = (const float*)d_in[0];
  const float* freqs = (const float*)d_in[1];
  const float* gains = (const float*)d_in[2];
  const float* qs    = (const float*)d_in[3];
  float* out = (float*)d_out;
  float* ws  = (float*)d_ws;
  float* coef   = ws;
  float* powers = ws + F_OFF_POW;
  float* t      = ws + F_OFF_T;
  float* gbuf   = ws + F_OFF_G;
  float* sbuf   = ws + F_OFF_SB;

  hipLaunchKernelGGL(setup_kernel, dim3(B_), dim3(256), 0, stream,
                     freqs, gains, qs, coef, powers);
  hipLaunchKernelGGL((pass_v3<false>), dim3(F_PCH / 64, SEQ), dim3(64), 0, stream,
                     audio, coef, (const float*)nullptr, t, (float*)nullptr);
  hipLaunchKernelGGL((scan_horner<false>), dim3(F_GRP / 256, SEQ), dim3(256),
                     0, stream, t, powers, gbuf, (const float*)nullptr);
  hipLaunchKernelGGL(scan_ks, dim3(SEQ), dim3(512), 0, stream,
                     gbuf, powers, sbuf);
  hipLaunchKernelGGL((scan_horner<true>), dim3(F_GRP / 256, SEQ), dim3(256),
                     0, stream, t, powers, (float*)nullptr, sbuf);
  hipLaunchKernelGGL((pass_v3<true>), dim3(F_PCH / 64, SEQ), dim3(64), 0, stream,
                     audio, coef, t, (float*)nullptr, out);
}